// Round 12
// baseline (947.570 us; speedup 1.0000x reference)
//
#include <hip/hip_runtime.h>
#include <hip/hip_bf16.h>

#define NN 50000
#define EE 800000
#define IN_DIM 64
#define HIDDEN 128
#define HEADS 4
#define HEAD_DIM 32
#define EDGE_DIM 6
#define LAYERS 2
#define NEG_SLOPE 0.2f
#define BN_EPS 1e-5f

#define SCAN_CHUNK 1024
#define NSB ((NN + SCAN_CHUNK - 1) / SCAN_CHUNK)   // 49 blocks

// ---------------------------------------------------------------------------
// Edge-index dtype armor: single-block sampled detector (no atomics).
// ---------------------------------------------------------------------------
__global__ void detect_layout(const int* __restrict__ ei, int* __restrict__ flag) {
    __shared__ int any;
    if (threadIdx.x == 0) any = 0;
    __syncthreads();
    int found = 0;
    #pragma unroll
    for (int k = 0; k < 16; ++k) {
        int e = threadIdx.x + k * 1024;       // first 16384 edges; 2e+1 << 1.6M
        if (ei[2 * e + 1] != 0) found = 1;
    }
    if (found) any = 1;                       // benign race: all writers write 1
    __syncthreads();
    if (threadIdx.x == 0) *flag = any;
}

__global__ void normalize_edges(const int* __restrict__ ei, const int* __restrict__ flag,
                                int* __restrict__ src, int* __restrict__ dst) {
    int e = blockIdx.x * 256 + threadIdx.x;
    if (e >= EE) return;
    int s, d;
    if (*flag == 0) {              // int64 layout: low words at even positions
        s = ei[2 * e];
        d = ei[2 * EE + 2 * e];
    } else {                       // int32 layout
        s = ei[e];
        d = ei[EE + e];
    }
    s = (s < 0) ? 0 : ((s >= NN) ? NN - 1 : s);
    d = (d < 0) ? 0 : ((d >= NN) ? NN - 1 : d);
    src[e] = s;
    dst[e] = d;
}

// ---------------------------------------------------------------------------
// Counting sort of edges by destination node
// ---------------------------------------------------------------------------
__global__ void count_edges(const int* __restrict__ dst, int* __restrict__ counts) {
    int e = blockIdx.x * 256 + threadIdx.x;
    if (e < EE) atomicAdd(&counts[dst[e]], 1);
}

__global__ void scan_partial(const int* __restrict__ counts, int* __restrict__ bsum) {
    __shared__ int ws[4];
    const int tid = threadIdx.x;
    const int lane = tid & 63, wid = tid >> 6;
    int i0 = blockIdx.x * SCAN_CHUNK + tid * 4;
    int s = 0;
    #pragma unroll
    for (int k = 0; k < 4; ++k) {
        int i = i0 + k;
        if (i < NN) s += counts[i];
    }
    #pragma unroll
    for (int ofs = 1; ofs < 64; ofs <<= 1) s += __shfl_xor(s, ofs, 64);
    if (lane == 0) ws[wid] = s;
    __syncthreads();
    if (tid == 0) bsum[blockIdx.x] = ws[0] + ws[1] + ws[2] + ws[3];
}

__global__ void scan_bsum(int* __restrict__ bsum) {
    int lane = threadIdx.x;
    int v = (lane < NSB) ? bsum[lane] : 0;
    int x = v;
    #pragma unroll
    for (int ofs = 1; ofs < 64; ofs <<= 1) {
        int t = __shfl_up(x, ofs, 64);
        if (lane >= ofs) x += t;
    }
    if (lane < NSB) bsum[lane] = x - v;   // exclusive
}

__global__ void scan_final(const int* __restrict__ counts, const int* __restrict__ bsumX,
                           int* __restrict__ offsets, int* __restrict__ cursor) {
    __shared__ int ws[4];
    const int tid = threadIdx.x;
    const int lane = tid & 63, wid = tid >> 6;
    const int b = blockIdx.x;
    int i0 = b * SCAN_CHUNK + tid * 4;
    int v[4];
    int tsum = 0;
    #pragma unroll
    for (int k = 0; k < 4; ++k) {
        int i = i0 + k;
        v[k] = (i < NN) ? counts[i] : 0;
        tsum += v[k];
    }
    int x = tsum;
    #pragma unroll
    for (int ofs = 1; ofs < 64; ofs <<= 1) {
        int t = __shfl_up(x, ofs, 64);
        if (lane >= ofs) x += t;
    }
    if (lane == 63) ws[wid] = x;
    __syncthreads();
    int woff = 0;
    for (int w = 0; w < wid; ++w) woff += ws[w];
    int excl = (x - tsum) + woff + bsumX[b];
    #pragma unroll
    for (int k = 0; k < 4; ++k) {
        int i = i0 + k;
        if (i < NN) { offsets[i] = excl; cursor[i] = excl; }
        excl += v[k];
    }
    if (b == 0 && tid == 0) offsets[NN] = EE;
}

__global__ void bucket_edges(const int* __restrict__ dst, int* __restrict__ cursor,
                             int* __restrict__ sorted) {
    int e = blockIdx.x * 256 + threadIdx.x;
    if (e < EE) {
        int p = atomicAdd(&cursor[dst[e]], 1);
        sorted[p] = e;
    }
}

// ---------------------------------------------------------------------------
// fp32 GEMM: out[n,128] = A[n,K] @ W[K,128] + b  (+ReLU). For input proj.
// ---------------------------------------------------------------------------
template <int K, bool RELU>
__launch_bounds__(256, 2)
__global__ void gemm_k(const float* __restrict__ A, const float* __restrict__ W,
                       const float* __restrict__ bias, float* __restrict__ out, int n) {
    constexpr int KC = 64;
    constexpr int NCH = K / KC;
    __shared__ float Ws[KC][128];   // 32 KB
    __shared__ float As[32][KC];    // 8 KB
    const int tid = threadIdx.x;
    const int tx = tid & 31;
    const int ty = tid >> 5;
    const int row0 = blockIdx.x * 32;

    float acc[4][4] = {};

    for (int ch = 0; ch < NCH; ++ch) {
        const float* Wp = W + ch * KC * 128;
        for (int i = tid * 4; i < KC * 128; i += 256 * 4)
            *(float4*)&((float*)Ws)[i] = *(const float4*)&Wp[i];
        for (int i = tid * 4; i < 32 * KC; i += 256 * 4) {
            int r = i / KC, c = i % KC;
            int gr = row0 + r;
            float4 v = {0.f, 0.f, 0.f, 0.f};
            if (gr < n) v = *(const float4*)&A[gr * K + ch * KC + c];
            *(float4*)&As[r][c] = v;
        }
        __syncthreads();

        #pragma unroll 4
        for (int k4 = 0; k4 < KC; k4 += 4) {
            float4 av4[4];
            float aa[4][4];
            #pragma unroll
            for (int i = 0; i < 4; ++i) av4[i] = *(float4*)&As[ty * 4 + i][k4];
            #pragma unroll
            for (int i = 0; i < 4; ++i) {
                aa[i][0] = av4[i].x; aa[i][1] = av4[i].y;
                aa[i][2] = av4[i].z; aa[i][3] = av4[i].w;
            }
            #pragma unroll
            for (int j = 0; j < 4; ++j) {
                float4 w = *(float4*)&Ws[k4 + j][tx * 4];
                #pragma unroll
                for (int i = 0; i < 4; ++i) {
                    acc[i][0] += aa[i][j] * w.x;
                    acc[i][1] += aa[i][j] * w.y;
                    acc[i][2] += aa[i][j] * w.z;
                    acc[i][3] += aa[i][j] * w.w;
                }
            }
        }
        __syncthreads();
    }

    float4 bv = *(const float4*)&bias[tx * 4];
    #pragma unroll
    for (int i = 0; i < 4; ++i) {
        int gr = row0 + ty * 4 + i;
        if (gr < n) {
            float4 o;
            o.x = acc[i][0] + bv.x;
            o.y = acc[i][1] + bv.y;
            o.z = acc[i][2] + bv.z;
            o.w = acc[i][3] + bv.w;
            if (RELU) {
                o.x = fmaxf(o.x, 0.f); o.y = fmaxf(o.y, 0.f);
                o.z = fmaxf(o.z, 0.f); o.w = fmaxf(o.w, 0.f);
            }
            *(float4*)&out[gr * 128 + tx * 4] = o;
        }
    }
}

// ---------------------------------------------------------------------------
// Dual fp32 GEMM sharing the A operand: out1 = A@W1+b1, out2 = A@W2+b2.
// ---------------------------------------------------------------------------
__launch_bounds__(256, 2)
__global__ void gemm_dual(const float* __restrict__ A,
                          const float* __restrict__ W1, const float* __restrict__ b1,
                          const float* __restrict__ W2, const float* __restrict__ b2,
                          float* __restrict__ out1, float* __restrict__ out2, int n) {
    constexpr int K = 128, KC = 32;
    __shared__ float W1s[KC][128];  // 16 KB
    __shared__ float W2s[KC][128];  // 16 KB
    __shared__ float As[32][KC];    // 4 KB
    const int tid = threadIdx.x;
    const int tx = tid & 31;
    const int ty = tid >> 5;
    const int row0 = blockIdx.x * 32;

    float acc1[4][4] = {}, acc2[4][4] = {};

    for (int ch = 0; ch < K / KC; ++ch) {
        const float* W1p = W1 + ch * KC * 128;
        const float* W2p = W2 + ch * KC * 128;
        for (int i = tid * 4; i < KC * 128; i += 256 * 4) {
            *(float4*)&((float*)W1s)[i] = *(const float4*)&W1p[i];
            *(float4*)&((float*)W2s)[i] = *(const float4*)&W2p[i];
        }
        {
            int i = tid * 4;
            int r = i / KC, c = i % KC;
            int gr = row0 + r;
            float4 v = {0.f, 0.f, 0.f, 0.f};
            if (gr < n) v = *(const float4*)&A[gr * K + ch * KC + c];
            *(float4*)&As[r][c] = v;
        }
        __syncthreads();

        #pragma unroll
        for (int k4 = 0; k4 < KC; k4 += 4) {
            float4 av4[4];
            float aa[4][4];
            #pragma unroll
            for (int i = 0; i < 4; ++i) av4[i] = *(float4*)&As[ty * 4 + i][k4];
            #pragma unroll
            for (int i = 0; i < 4; ++i) {
                aa[i][0] = av4[i].x; aa[i][1] = av4[i].y;
                aa[i][2] = av4[i].z; aa[i][3] = av4[i].w;
            }
            #pragma unroll
            for (int j = 0; j < 4; ++j) {
                float4 w1 = *(float4*)&W1s[k4 + j][tx * 4];
                float4 w2 = *(float4*)&W2s[k4 + j][tx * 4];
                #pragma unroll
                for (int i = 0; i < 4; ++i) {
                    acc1[i][0] += aa[i][j] * w1.x;
                    acc1[i][1] += aa[i][j] * w1.y;
                    acc1[i][2] += aa[i][j] * w1.z;
                    acc1[i][3] += aa[i][j] * w1.w;
                    acc2[i][0] += aa[i][j] * w2.x;
                    acc2[i][1] += aa[i][j] * w2.y;
                    acc2[i][2] += aa[i][j] * w2.z;
                    acc2[i][3] += aa[i][j] * w2.w;
                }
            }
        }
        __syncthreads();
    }

    float4 bv1 = *(const float4*)&b1[tx * 4];
    float4 bv2 = *(const float4*)&b2[tx * 4];
    #pragma unroll
    for (int i = 0; i < 4; ++i) {
        int gr = row0 + ty * 4 + i;
        if (gr < n) {
            float4 o1, o2;
            o1.x = acc1[i][0] + bv1.x; o1.y = acc1[i][1] + bv1.y;
            o1.z = acc1[i][2] + bv1.z; o1.w = acc1[i][3] + bv1.w;
            o2.x = acc2[i][0] + bv2.x; o2.y = acc2[i][1] + bv2.y;
            o2.z = acc2[i][2] + bv2.z; o2.w = acc2[i][3] + bv2.w;
            *(float4*)&out1[gr * 128 + tx * 4] = o1;
            *(float4*)&out2[gr * 128 + tx * 4] = o2;
        }
    }
}

// ---------------------------------------------------------------------------
// Fused GATv2 aggregation v3: one wave per destination node, split into FOUR
// 16-lane groups; each group owns one edge per iteration (8 ch/lane), so 4
// edges are in flight concurrently. Per-head logit reduce = 2 shfl_xor (bits
// 0-1, within each 4-lane head cluster) executed by ALL lanes with uniform
// guards; group-uniform validity guards touch scalar state only. Four online
// softmax states merged by a 2-stage butterfly (xor 16, 32) at node end.
// ---------------------------------------------------------------------------
__launch_bounds__(256, 4)
__global__ void gat_agg(const float* __restrict__ xl, const float* __restrict__ xr,
                        const float* __restrict__ edge_attr,
                        const int* __restrict__ src,
                        const int* __restrict__ sorted, const int* __restrict__ offsets,
                        const float* __restrict__ We, const float* __restrict__ be,
                        const float* __restrict__ att, const float* __restrict__ cbias,
                        float* __restrict__ y) {
    __shared__ float sWe[EDGE_DIM][128];
    __shared__ float sbe[128];
    __shared__ float satt[128];
    __shared__ float scb[128];
    const int tid = threadIdx.x;
    for (int i = tid; i < EDGE_DIM * 128; i += 256) ((float*)sWe)[i] = We[i];
    if (tid < 128) { sbe[tid] = be[tid]; satt[tid] = att[tid]; scb[tid] = cbias[tid]; }
    __syncthreads();

    const int wid = tid >> 6, lane = tid & 63;
    const int node = blockIdx.x * 4 + wid;
    if (node >= NN) return;

    const int g  = lane >> 4;        // group 0..3 (uniform within 16-lane group)
    const int gl = lane & 15;        // lane within group
    const int c0 = gl * 8;           // this lane's 8 channels

    float4 xr0 = *(const float4*)&xr[(size_t)node * 128 + c0];
    float4 xr1 = *(const float4*)&xr[(size_t)node * 128 + c0 + 4];
    float4 at0 = *(const float4*)&satt[c0];
    float4 at1 = *(const float4*)&satt[c0 + 4];
    float4 be0 = *(const float4*)&sbe[c0];
    float4 be1 = *(const float4*)&sbe[c0 + 4];
    // per-lane constant base = xr + be
    float4 b0, b1;
    b0.x = xr0.x + be0.x; b0.y = xr0.y + be0.y; b0.z = xr0.z + be0.z; b0.w = xr0.w + be0.w;
    b1.x = xr1.x + be1.x; b1.y = xr1.y + be1.y; b1.z = xr1.z + be1.z; b1.w = xr1.w + be1.w;

    const int off = offsets[node];
    const int deg = offsets[node + 1] - off;

    float m = -1e30f, d = 0.f;
    float4 a0 = {0.f, 0.f, 0.f, 0.f}, a1 = {0.f, 0.f, 0.f, 0.f};

    for (int base = 0; base < deg; base += 4) {
        const int idx  = base + g;                 // this group's edge
        const int cidx = (idx < deg) ? idx : deg - 1;   // clamped (valid)
        const int eid = sorted[off + cidx];        // group-broadcast loads
        const int s   = src[eid];
        const float* xp = &xl[(size_t)s * 128 + c0];
        float4 x0 = *(const float4*)xp;
        float4 x1 = *(const float4*)(xp + 4);
        const float* pe = &edge_attr[(size_t)eid * EDGE_DIM];

        float4 m0, m1;
        m0.x = x0.x + b0.x; m0.y = x0.y + b0.y; m0.z = x0.z + b0.z; m0.w = x0.w + b0.w;
        m1.x = x1.x + b1.x; m1.y = x1.y + b1.y; m1.z = x1.z + b1.z; m1.w = x1.w + b1.w;
        #pragma unroll
        for (int k = 0; k < EDGE_DIM; ++k) {
            float v = pe[k];
            float4 w0 = *(const float4*)&sWe[k][c0];
            float4 w1 = *(const float4*)&sWe[k][c0 + 4];
            m0.x += v * w0.x; m0.y += v * w0.y; m0.z += v * w0.z; m0.w += v * w0.w;
            m1.x += v * w1.x; m1.y += v * w1.y; m1.z += v * w1.z; m1.w += v * w1.w;
        }
        m0.x = (m0.x > 0.f) ? m0.x : m0.x * NEG_SLOPE;
        m0.y = (m0.y > 0.f) ? m0.y : m0.y * NEG_SLOPE;
        m0.z = (m0.z > 0.f) ? m0.z : m0.z * NEG_SLOPE;
        m0.w = (m0.w > 0.f) ? m0.w : m0.w * NEG_SLOPE;
        m1.x = (m1.x > 0.f) ? m1.x : m1.x * NEG_SLOPE;
        m1.y = (m1.y > 0.f) ? m1.y : m1.y * NEG_SLOPE;
        m1.z = (m1.z > 0.f) ? m1.z : m1.z * NEG_SLOPE;
        m1.w = (m1.w > 0.f) ? m1.w : m1.w * NEG_SLOPE;

        float t = m0.x * at0.x + m0.y * at0.y + m0.z * at0.z + m0.w * at0.w
                + m1.x * at1.x + m1.y * at1.y + m1.z * at1.z + m1.w * at1.w;
        // head = 32 ch = 4 lanes (8 ch each); reduce over lane bits 0-1
        t += __shfl_xor(t, 1, 64);
        t += __shfl_xor(t, 2, 64);

        if (idx < deg) {   // uniform within the 16-lane group; scalar ops only
            float nm = fmaxf(m, t);
            float sc = __expf(m - nm);
            float p  = __expf(t - nm);
            d = d * sc + p;
            a0.x = a0.x * sc + p * x0.x; a0.y = a0.y * sc + p * x0.y;
            a0.z = a0.z * sc + p * x0.z; a0.w = a0.w * sc + p * x0.w;
            a1.x = a1.x * sc + p * x1.x; a1.y = a1.y * sc + p * x1.y;
            a1.z = a1.z * sc + p * x1.z; a1.w = a1.w * sc + p * x1.w;
            m = nm;
        }
    }

    // butterfly merge of the 4 group states (lanes gl, gl+16, gl+32, gl+48
    // hold the same channels); all lanes active, uniform control flow
    #pragma unroll
    for (int ofs = 16; ofs <= 32; ofs <<= 1) {
        float mo = __shfl_xor(m, ofs, 64);
        float do_ = __shfl_xor(d, ofs, 64);
        float4 p0, p1;
        p0.x = __shfl_xor(a0.x, ofs, 64); p0.y = __shfl_xor(a0.y, ofs, 64);
        p0.z = __shfl_xor(a0.z, ofs, 64); p0.w = __shfl_xor(a0.w, ofs, 64);
        p1.x = __shfl_xor(a1.x, ofs, 64); p1.y = __shfl_xor(a1.y, ofs, 64);
        p1.z = __shfl_xor(a1.z, ofs, 64); p1.w = __shfl_xor(a1.w, ofs, 64);
        float M  = fmaxf(m, mo);
        float s1 = __expf(m - M);
        float s2 = __expf(mo - M);
        d = d * s1 + do_ * s2;
        a0.x = a0.x * s1 + p0.x * s2; a0.y = a0.y * s1 + p0.y * s2;
        a0.z = a0.z * s1 + p0.z * s2; a0.w = a0.w * s1 + p0.w * s2;
        a1.x = a1.x * s1 + p1.x * s2; a1.y = a1.y * s1 + p1.y * s2;
        a1.z = a1.z * s1 + p1.z * s2; a1.w = a1.w * s1 + p1.w * s2;
        m = M;
    }

    if (g == 0) {   // group 0 writes the node's 128 channels (512 B)
        float4 cb0 = *(const float4*)&scb[c0];
        float4 cb1 = *(const float4*)&scb[c0 + 4];
        float4 o0 = cb0, o1 = cb1;
        if (deg > 0) {
            float inv = 1.f / d;
            o0.x += a0.x * inv; o0.y += a0.y * inv;
            o0.z += a0.z * inv; o0.w += a0.w * inv;
            o1.x += a1.x * inv; o1.y += a1.y * inv;
            o1.z += a1.z * inv; o1.w += a1.w * inv;
        }
        *(float4*)&y[(size_t)node * 128 + c0]     = o0;
        *(float4*)&y[(size_t)node * 128 + c0 + 4] = o1;
    }
}

// ---------------------------------------------------------------------------
// BatchNorm: per-channel stats then apply + ReLU
// ---------------------------------------------------------------------------
__global__ void bn_stats(const float* __restrict__ y, float* __restrict__ gsum,
                         float* __restrict__ gsq) {
    __shared__ float ls[128], lq[128];
    const int tid = threadIdx.x;
    if (tid < 128) { ls[tid] = 0.f; lq[tid] = 0.f; }
    __syncthreads();
    int idx = blockIdx.x * 256 + tid;        // float4 units
    const int stride = gridDim.x * 256;
    const int c4 = (idx & 31) * 4;
    float s[4] = {}, q[4] = {};
    for (; idx < NN * 32; idx += stride) {
        float4 v = ((const float4*)y)[idx];
        s[0] += v.x; q[0] += v.x * v.x;
        s[1] += v.y; q[1] += v.y * v.y;
        s[2] += v.z; q[2] += v.z * v.z;
        s[3] += v.w; q[3] += v.w * v.w;
    }
    #pragma unroll
    for (int j = 0; j < 4; ++j) {
        atomicAdd(&ls[c4 + j], s[j]);
        atomicAdd(&lq[c4 + j], q[j]);
    }
    __syncthreads();
    if (tid < 128) {
        atomicAdd(&gsum[tid], ls[tid]);
        atomicAdd(&gsq[tid],  lq[tid]);
    }
}

__global__ void bn_apply(const float* __restrict__ y, const float* __restrict__ gsum,
                         const float* __restrict__ gsq, const float* __restrict__ gamma,
                         const float* __restrict__ beta, float* __restrict__ out) {
    int idx = blockIdx.x * 256 + threadIdx.x;   // float4 index
    const int stride = gridDim.x * 256;
    const int c4 = (idx & 31) * 4;
    const float invN = 1.f / (float)NN;
    float sc[4], sh[4];
    #pragma unroll
    for (int j = 0; j < 4; ++j) {
        int c = c4 + j;
        float mu  = gsum[c] * invN;
        float var = fmaxf(gsq[c] * invN - mu * mu, 0.f);
        sc[j] = rsqrtf(var + BN_EPS) * gamma[c];
        sh[j] = beta[c] - mu * sc[j];
    }
    for (; idx < NN * 32; idx += stride) {
        float4 v = ((const float4*)y)[idx];
        float4 o;
        o.x = fmaxf(v.x * sc[0] + sh[0], 0.f);
        o.y = fmaxf(v.y * sc[1] + sh[1], 0.f);
        o.z = fmaxf(v.z * sc[2] + sh[2], 0.f);
        o.w = fmaxf(v.w * sc[3] + sh[3], 0.f);
        ((float4*)out)[idx] = o;
    }
}

// ---------------------------------------------------------------------------
extern "C" void kernel_launch(void* const* d_in, const int* in_sizes, int n_in,
                              void* d_out, int out_size, void* d_ws, size_t ws_size,
                              hipStream_t stream) {
    const float* x        = (const float*)d_in[0];
    const int*   eidx     = (const int*)d_in[1];      // [2,E], layout auto-detected
    const float* edge_attr= (const float*)d_in[2];
    const float* Wproj    = (const float*)d_in[3];
    const float* bproj    = (const float*)d_in[4];
    const float* Wl       = (const float*)d_in[5];
    const float* bl       = (const float*)d_in[6];
    const float* Wr       = (const float*)d_in[7];
    const float* br       = (const float*)d_in[8];
    const float* We       = (const float*)d_in[9];
    const float* be       = (const float*)d_in[10];
    const float* att      = (const float*)d_in[11];
    const float* cbias    = (const float*)d_in[12];
    const float* gamma    = (const float*)d_in[13];
    const float* beta     = (const float*)d_in[14];

    char* ws = (char*)d_ws;
    auto alloc = [&](size_t bytes) {
        char* p = ws;
        ws += (bytes + 255) & ~(size_t)255;
        return p;
    };
    float* h      = (float*)alloc((size_t)NN * 128 * 4);  // pre-BN buffer (in-place BN)
    float* xlB    = (float*)alloc((size_t)NN * 128 * 4);
    float* xrB    = (float*)alloc((size_t)NN * 128 * 4);
    int*   srcN   = (int*)alloc((size_t)EE * 4);
    int*   dstN   = (int*)alloc((size_t)EE * 4);
    int*   counts = (int*)alloc((size_t)NN * 4);
    int*   offs   = (int*)alloc((size_t)(NN + 1) * 4);
    int*   cursor = (int*)alloc((size_t)NN * 4);
    int*   sorted = (int*)alloc((size_t)EE * 4);
    int*   bsum   = (int*)alloc((size_t)NSB * 4);
    int*   flag   = (int*)alloc(256);
    float* gsum   = (float*)alloc((size_t)LAYERS * 128 * 4);
    float* gsq    = (float*)alloc((size_t)LAYERS * 128 * 4);

    hipMemsetAsync(counts, 0, (size_t)NN * 4, stream);
    hipMemsetAsync(gsum, 0, (size_t)LAYERS * 128 * 4, stream);
    hipMemsetAsync(gsq,  0, (size_t)LAYERS * 128 * 4, stream);

    // normalize edge_index to int32 src/dst regardless of int32/int64 layout
    detect_layout<<<1, 1024, 0, stream>>>(eidx, flag);
    normalize_edges<<<(EE + 255) / 256, 256, 0, stream>>>(eidx, flag, srcN, dstN);

    // bucket edges by dst (parallel counting sort, shared by both layers)
    count_edges<<<(EE + 255) / 256, 256, 0, stream>>>(dstN, counts);
    scan_partial<<<NSB, 256, 0, stream>>>(counts, bsum);
    scan_bsum<<<1, 64, 0, stream>>>(bsum);
    scan_final<<<NSB, 256, 0, stream>>>(counts, bsum, offs, cursor);
    bucket_edges<<<(EE + 255) / 256, 256, 0, stream>>>(dstN, cursor, sorted);

    // input projection + ReLU
    gemm_k<IN_DIM, true><<<(NN + 31) / 32, 256, 0, stream>>>(x, Wproj, bproj, h, NN);

    for (int l = 0; l < LAYERS; ++l) {
        gemm_dual<<<(NN + 31) / 32, 256, 0, stream>>>(
            h,
            Wl + (size_t)l * 128 * 128, bl + l * 128,
            Wr + (size_t)l * 128 * 128, br + l * 128,
            xlB, xrB, NN);
        gat_agg<<<(NN + 3) / 4, 256, 0, stream>>>(
            xlB, xrB, edge_attr, srcN, sorted, offs,
            We + (size_t)l * EDGE_DIM * 128, be + l * 128, att + l * 128,
            cbias + l * 128, h);
        bn_stats<<<400, 256, 0, stream>>>(h, gsum + l * 128, gsq + l * 128);
        float* outp = (l == LAYERS - 1) ? (float*)d_out : h;
        bn_apply<<<512, 256, 0, stream>>>(h, gsum + l * 128, gsq + l * 128,
                                          gamma + l * 128, beta + l * 128, outp);
    }
}

// Round 14
// 823.033 us; speedup vs baseline: 1.1513x; 1.1513x over previous
//
#include <hip/hip_runtime.h>
#include <hip/hip_bf16.h>

#define NN 50000
#define EE 800000
#define IN_DIM 64
#define HIDDEN 128
#define HEADS 4
#define HEAD_DIM 32
#define EDGE_DIM 6
#define LAYERS 2
#define NEG_SLOPE 0.2f
#define BN_EPS 1e-5f

#define SCAN_CHUNK 1024
#define NSB ((NN + SCAN_CHUNK - 1) / SCAN_CHUNK)   // 49 blocks

__device__ __forceinline__ unsigned bf2pack(float a, float b) {
    unsigned ua = __float_as_uint(a); ua = (ua + 0x7FFFu + ((ua >> 16) & 1u)) >> 16;
    unsigned ub = __float_as_uint(b); ub = (ub + 0x7FFFu + ((ub >> 16) & 1u)) >> 16;
    return ua | (ub << 16);
}
__device__ __forceinline__ float bf_lo(unsigned u) { return __uint_as_float(u << 16); }
__device__ __forceinline__ float bf_hi(unsigned u) { return __uint_as_float(u & 0xFFFF0000u); }

// ---------------------------------------------------------------------------
// Edge-index dtype armor: single-block sampled detector (no atomics).
// ---------------------------------------------------------------------------
__global__ void detect_layout(const int* __restrict__ ei, int* __restrict__ flag) {
    __shared__ int any;
    if (threadIdx.x == 0) any = 0;
    __syncthreads();
    int found = 0;
    #pragma unroll
    for (int k = 0; k < 16; ++k) {
        int e = threadIdx.x + k * 1024;       // first 16384 edges; 2e+1 << 1.6M
        if (ei[2 * e + 1] != 0) found = 1;
    }
    if (found) any = 1;                       // benign race: all writers write 1
    __syncthreads();
    if (threadIdx.x == 0) *flag = any;
}

__global__ void normalize_edges(const int* __restrict__ ei, const int* __restrict__ flag,
                                int* __restrict__ src, int* __restrict__ dst) {
    int e = blockIdx.x * 256 + threadIdx.x;
    if (e >= EE) return;
    int s, d;
    if (*flag == 0) {              // int64 layout: low words at even positions
        s = ei[2 * e];
        d = ei[2 * EE + 2 * e];
    } else {                       // int32 layout
        s = ei[e];
        d = ei[EE + e];
    }
    s = (s < 0) ? 0 : ((s >= NN) ? NN - 1 : s);
    d = (d < 0) ? 0 : ((d >= NN) ? NN - 1 : d);
    src[e] = s;
    dst[e] = d;
}

// ---------------------------------------------------------------------------
// Counting sort of edges by destination node
// ---------------------------------------------------------------------------
__global__ void count_edges(const int* __restrict__ dst, int* __restrict__ counts) {
    int e = blockIdx.x * 256 + threadIdx.x;
    if (e < EE) atomicAdd(&counts[dst[e]], 1);
}

__global__ void scan_partial(const int* __restrict__ counts, int* __restrict__ bsum) {
    __shared__ int ws[4];
    const int tid = threadIdx.x;
    const int lane = tid & 63, wid = tid >> 6;
    int i0 = blockIdx.x * SCAN_CHUNK + tid * 4;
    int s = 0;
    #pragma unroll
    for (int k = 0; k < 4; ++k) {
        int i = i0 + k;
        if (i < NN) s += counts[i];
    }
    #pragma unroll
    for (int ofs = 1; ofs < 64; ofs <<= 1) s += __shfl_xor(s, ofs, 64);
    if (lane == 0) ws[wid] = s;
    __syncthreads();
    if (tid == 0) bsum[blockIdx.x] = ws[0] + ws[1] + ws[2] + ws[3];
}

__global__ void scan_bsum(int* __restrict__ bsum) {
    int lane = threadIdx.x;
    int v = (lane < NSB) ? bsum[lane] : 0;
    int x = v;
    #pragma unroll
    for (int ofs = 1; ofs < 64; ofs <<= 1) {
        int t = __shfl_up(x, ofs, 64);
        if (lane >= ofs) x += t;
    }
    if (lane < NSB) bsum[lane] = x - v;   // exclusive
}

__global__ void scan_final(const int* __restrict__ counts, const int* __restrict__ bsumX,
                           int* __restrict__ offsets, int* __restrict__ cursor) {
    __shared__ int ws[4];
    const int tid = threadIdx.x;
    const int lane = tid & 63, wid = tid >> 6;
    const int b = blockIdx.x;
    int i0 = b * SCAN_CHUNK + tid * 4;
    int v[4];
    int tsum = 0;
    #pragma unroll
    for (int k = 0; k < 4; ++k) {
        int i = i0 + k;
        v[k] = (i < NN) ? counts[i] : 0;
        tsum += v[k];
    }
    int x = tsum;
    #pragma unroll
    for (int ofs = 1; ofs < 64; ofs <<= 1) {
        int t = __shfl_up(x, ofs, 64);
        if (lane >= ofs) x += t;
    }
    if (lane == 63) ws[wid] = x;
    __syncthreads();
    int woff = 0;
    for (int w = 0; w < wid; ++w) woff += ws[w];
    int excl = (x - tsum) + woff + bsumX[b];
    #pragma unroll
    for (int k = 0; k < 4; ++k) {
        int i = i0 + k;
        if (i < NN) { offsets[i] = excl; cursor[i] = excl; }
        excl += v[k];
    }
    if (b == 0 && tid == 0) offsets[NN] = EE;
}

// Bucket pass: emit src and edge attrs (bf16) in dst-sorted order, so the hot
// aggregation loop reads only coalesced / line-shared streams (no random
// per-edge line pulls for src[eid] / edge_attr[eid], no edge ids at all).
__global__ void bucket_edges(const int* __restrict__ dst, const int* __restrict__ srcN,
                             const float* __restrict__ ea, int* __restrict__ cursor,
                             int* __restrict__ ssrc, unsigned* __restrict__ eattr_s) {
    int e = blockIdx.x * 256 + threadIdx.x;
    if (e < EE) {
        int p = atomicAdd(&cursor[dst[e]], 1);
        ssrc[p] = srcN[e];
        const float* a = &ea[(size_t)e * EDGE_DIM];
        unsigned* o = eattr_s + (size_t)p * 3;
        o[0] = bf2pack(a[0], a[1]);
        o[1] = bf2pack(a[2], a[3]);
        o[2] = bf2pack(a[4], a[5]);
    }
}

// ---------------------------------------------------------------------------
// fp32 GEMM: out[n,128] = A[n,K] @ W[K,128] + b  (+ReLU). For input proj.
// ---------------------------------------------------------------------------
template <int K, bool RELU>
__launch_bounds__(256, 2)
__global__ void gemm_k(const float* __restrict__ A, const float* __restrict__ W,
                       const float* __restrict__ bias, float* __restrict__ out, int n) {
    constexpr int KC = 64;
    constexpr int NCH = K / KC;
    __shared__ float Ws[KC][128];   // 32 KB
    __shared__ float As[32][KC];    // 8 KB
    const int tid = threadIdx.x;
    const int tx = tid & 31;
    const int ty = tid >> 5;
    const int row0 = blockIdx.x * 32;

    float acc[4][4] = {};

    for (int ch = 0; ch < NCH; ++ch) {
        const float* Wp = W + ch * KC * 128;
        for (int i = tid * 4; i < KC * 128; i += 256 * 4)
            *(float4*)&((float*)Ws)[i] = *(const float4*)&Wp[i];
        for (int i = tid * 4; i < 32 * KC; i += 256 * 4) {
            int r = i / KC, c = i % KC;
            int gr = row0 + r;
            float4 v = {0.f, 0.f, 0.f, 0.f};
            if (gr < n) v = *(const float4*)&A[gr * K + ch * KC + c];
            *(float4*)&As[r][c] = v;
        }
        __syncthreads();

        #pragma unroll 4
        for (int k4 = 0; k4 < KC; k4 += 4) {
            float4 av4[4];
            float aa[4][4];
            #pragma unroll
            for (int i = 0; i < 4; ++i) av4[i] = *(float4*)&As[ty * 4 + i][k4];
            #pragma unroll
            for (int i = 0; i < 4; ++i) {
                aa[i][0] = av4[i].x; aa[i][1] = av4[i].y;
                aa[i][2] = av4[i].z; aa[i][3] = av4[i].w;
            }
            #pragma unroll
            for (int j = 0; j < 4; ++j) {
                float4 w = *(float4*)&Ws[k4 + j][tx * 4];
                #pragma unroll
                for (int i = 0; i < 4; ++i) {
                    acc[i][0] += aa[i][j] * w.x;
                    acc[i][1] += aa[i][j] * w.y;
                    acc[i][2] += aa[i][j] * w.z;
                    acc[i][3] += aa[i][j] * w.w;
                }
            }
        }
        __syncthreads();
    }

    float4 bv = *(const float4*)&bias[tx * 4];
    #pragma unroll
    for (int i = 0; i < 4; ++i) {
        int gr = row0 + ty * 4 + i;
        if (gr < n) {
            float4 o;
            o.x = acc[i][0] + bv.x;
            o.y = acc[i][1] + bv.y;
            o.z = acc[i][2] + bv.z;
            o.w = acc[i][3] + bv.w;
            if (RELU) {
                o.x = fmaxf(o.x, 0.f); o.y = fmaxf(o.y, 0.f);
                o.z = fmaxf(o.z, 0.f); o.w = fmaxf(o.w, 0.f);
            }
            *(float4*)&out[gr * 128 + tx * 4] = o;
        }
    }
}

// ---------------------------------------------------------------------------
// Dual fp32 GEMM sharing the A operand. out1 (xl) stored as bf16 (halves the
// gather traffic downstream); out2 (xr) stays fp32.
// ---------------------------------------------------------------------------
__launch_bounds__(256, 2)
__global__ void gemm_dual(const float* __restrict__ A,
                          const float* __restrict__ W1, const float* __restrict__ b1,
                          const float* __restrict__ W2, const float* __restrict__ b2,
                          unsigned short* __restrict__ out1, float* __restrict__ out2,
                          int n) {
    constexpr int K = 128, KC = 32;
    __shared__ float W1s[KC][128];  // 16 KB
    __shared__ float W2s[KC][128];  // 16 KB
    __shared__ float As[32][KC];    // 4 KB
    const int tid = threadIdx.x;
    const int tx = tid & 31;
    const int ty = tid >> 5;
    const int row0 = blockIdx.x * 32;

    float acc1[4][4] = {}, acc2[4][4] = {};

    for (int ch = 0; ch < K / KC; ++ch) {
        const float* W1p = W1 + ch * KC * 128;
        const float* W2p = W2 + ch * KC * 128;
        for (int i = tid * 4; i < KC * 128; i += 256 * 4) {
            *(float4*)&((float*)W1s)[i] = *(const float4*)&W1p[i];
            *(float4*)&((float*)W2s)[i] = *(const float4*)&W2p[i];
        }
        {
            int i = tid * 4;
            int r = i / KC, c = i % KC;
            int gr = row0 + r;
            float4 v = {0.f, 0.f, 0.f, 0.f};
            if (gr < n) v = *(const float4*)&A[gr * K + ch * KC + c];
            *(float4*)&As[r][c] = v;
        }
        __syncthreads();

        #pragma unroll
        for (int k4 = 0; k4 < KC; k4 += 4) {
            float4 av4[4];
            float aa[4][4];
            #pragma unroll
            for (int i = 0; i < 4; ++i) av4[i] = *(float4*)&As[ty * 4 + i][k4];
            #pragma unroll
            for (int i = 0; i < 4; ++i) {
                aa[i][0] = av4[i].x; aa[i][1] = av4[i].y;
                aa[i][2] = av4[i].z; aa[i][3] = av4[i].w;
            }
            #pragma unroll
            for (int j = 0; j < 4; ++j) {
                float4 w1 = *(float4*)&W1s[k4 + j][tx * 4];
                float4 w2 = *(float4*)&W2s[k4 + j][tx * 4];
                #pragma unroll
                for (int i = 0; i < 4; ++i) {
                    acc1[i][0] += aa[i][j] * w1.x;
                    acc1[i][1] += aa[i][j] * w1.y;
                    acc1[i][2] += aa[i][j] * w1.z;
                    acc1[i][3] += aa[i][j] * w1.w;
                    acc2[i][0] += aa[i][j] * w2.x;
                    acc2[i][1] += aa[i][j] * w2.y;
                    acc2[i][2] += aa[i][j] * w2.z;
                    acc2[i][3] += aa[i][j] * w2.w;
                }
            }
        }
        __syncthreads();
    }

    float4 bv1 = *(const float4*)&b1[tx * 4];
    float4 bv2 = *(const float4*)&b2[tx * 4];
    #pragma unroll
    for (int i = 0; i < 4; ++i) {
        int gr = row0 + ty * 4 + i;
        if (gr < n) {
            float o1x = acc1[i][0] + bv1.x, o1y = acc1[i][1] + bv1.y;
            float o1z = acc1[i][2] + bv1.z, o1w = acc1[i][3] + bv1.w;
            float4 o2;
            o2.x = acc2[i][0] + bv2.x; o2.y = acc2[i][1] + bv2.y;
            o2.z = acc2[i][2] + bv2.z; o2.w = acc2[i][3] + bv2.w;
            uint2 pk;
            pk.x = bf2pack(o1x, o1y);
            pk.y = bf2pack(o1z, o1w);
            *(uint2*)&out1[gr * 128 + tx * 4] = pk;
            *(float4*)&out2[gr * 128 + tx * 4] = o2;
        }
    }
}

// ---------------------------------------------------------------------------
// Fused GATv2 aggregation v4 = R6-validated v2 structure (one wave per node,
// 2 channels/lane, serial broadcast loop, 2-edge unroll with dual online-
// softmax states) with low-traffic operand streams: bf16 xl gathers (4B/lane),
// coalesced ssrc reads, broadcast bf16 eattr reads. No edge ids in hot loop.
// ---------------------------------------------------------------------------
__launch_bounds__(256, 8)
__global__ void gat_agg(const unsigned short* __restrict__ xl,   // bf16 [N][128]
                        const float* __restrict__ xr,
                        const unsigned* __restrict__ eattr_s,    // bf16x6 [E] sorted
                        const int* __restrict__ ssrc,            // [E] sorted src
                        const int* __restrict__ offsets,
                        const float* __restrict__ We, const float* __restrict__ be,
                        const float* __restrict__ att, const float* __restrict__ cbias,
                        float* __restrict__ y) {
    __shared__ float sWe[EDGE_DIM][128];
    __shared__ float sbe[128];
    __shared__ float satt[128];
    __shared__ float scb[128];
    const int tid = threadIdx.x;
    for (int i = tid; i < EDGE_DIM * 128; i += 256) ((float*)sWe)[i] = We[i];
    if (tid < 128) { sbe[tid] = be[tid]; satt[tid] = att[tid]; scb[tid] = cbias[tid]; }
    __syncthreads();

    const int wid = tid >> 6, lane = tid & 63;
    const int node = blockIdx.x * 4 + wid;
    if (node >= NN) return;

    const int c0 = lane * 2;       // this lane's 2 channels
    float2 xrv  = *(const float2*)&xr[(size_t)node * 128 + c0];
    float2 attv = *(const float2*)&satt[c0];
    float2 bev  = *(const float2*)&sbe[c0];
    const float base0 = xrv.x + bev.x;
    const float base1 = xrv.y + bev.y;

    const int off = offsets[node];
    const int deg = offsets[node + 1] - off;

    float mA = -1e30f, dA = 0.f, aA0 = 0.f, aA1 = 0.f;
    float mB = -1e30f, dB = 0.f, aB0 = 0.f, aB1 = 0.f;

    for (int chunk = 0; chunk < deg; chunk += 64) {
        int i = chunk + lane;
        int sL = 0;
        if (i < deg) sL = ssrc[off + i];           // coalesced 4B stream
        const int cnt = min(64, deg - chunk);      // wave-uniform
        const unsigned* ep = eattr_s + (size_t)(off + chunk) * 3;  // uniform base

        for (int j = 0; j < cnt; j += 2) {
            const bool hb = (j + 1 < cnt);          // wave-uniform
            const int jb = hb ? j + 1 : j;          // valid index always
            int sa = __shfl(sL, j, 64);
            int sb = __shfl(sL, jb, 64);
            // two bf16 gathers in flight (4 B per lane, 256 B per wave each)
            unsigned xa_u = *(const unsigned*)&xl[(size_t)sa * 128 + c0];
            unsigned xb_u = *(const unsigned*)&xl[(size_t)sb * 128 + c0];
            // broadcast bf16 edge attrs (uniform address, line-shared)
            unsigned ea0 = ep[j * 3], ea1 = ep[j * 3 + 1], ea2 = ep[j * 3 + 2];
            unsigned eb0 = ep[jb * 3], eb1 = ep[jb * 3 + 1], eb2 = ep[jb * 3 + 2];

            float xa0 = bf_lo(xa_u), xa1 = bf_hi(xa_u);
            float xb0 = bf_lo(xb_u), xb1 = bf_hi(xb_u);
            float eav[6] = {bf_lo(ea0), bf_hi(ea0), bf_lo(ea1),
                            bf_hi(ea1), bf_lo(ea2), bf_hi(ea2)};
            float ebv[6] = {bf_lo(eb0), bf_hi(eb0), bf_lo(eb1),
                            bf_hi(eb1), bf_lo(eb2), bf_hi(eb2)};

            float ma0 = xa0 + base0, ma1 = xa1 + base1;
            float mb0 = xb0 + base0, mb1 = xb1 + base1;
            #pragma unroll
            for (int k = 0; k < EDGE_DIM; ++k) {
                float2 w = *(const float2*)&sWe[k][c0];
                ma0 += eav[k] * w.x; ma1 += eav[k] * w.y;
                mb0 += ebv[k] * w.x; mb1 += ebv[k] * w.y;
            }
            ma0 = (ma0 > 0.f) ? ma0 : ma0 * NEG_SLOPE;
            ma1 = (ma1 > 0.f) ? ma1 : ma1 * NEG_SLOPE;
            mb0 = (mb0 > 0.f) ? mb0 : mb0 * NEG_SLOPE;
            mb1 = (mb1 > 0.f) ? mb1 : mb1 * NEG_SLOPE;
            float ta = ma0 * attv.x + ma1 * attv.y;
            float tb = mb0 * attv.x + mb1 * attv.y;
            // head = 32 channels = 16 consecutive lanes; reduce over bits 0-3
            #pragma unroll
            for (int ofs = 1; ofs <= 8; ofs <<= 1) {
                ta += __shfl_xor(ta, ofs, 64);
                tb += __shfl_xor(tb, ofs, 64);
            }
            {   // state A (edge j always valid)
                float nm = fmaxf(mA, ta);
                float sc = __expf(mA - nm);
                float p  = __expf(ta - nm);
                dA  = dA * sc + p;
                aA0 = aA0 * sc + p * xa0;
                aA1 = aA1 * sc + p * xa1;
                mA = nm;
            }
            if (hb) {   // wave-uniform
                float nm = fmaxf(mB, tb);
                float sc = __expf(mB - nm);
                float p  = __expf(tb - nm);
                dB  = dB * sc + p;
                aB0 = aB0 * sc + p * xb0;
                aB1 = aB1 * sc + p * xb1;
                mB = nm;
            }
        }
    }

    // lane-local merge of states A and B
    float o0 = scb[c0], o1 = scb[c0 + 1];
    if (deg > 0) {
        float M  = fmaxf(mA, mB);
        float sA = __expf(mA - M);      // mB may be -1e30 -> sB underflows to 0
        float sB = __expf(mB - M);
        float den = dA * sA + dB * sB;
        float inv = 1.f / den;
        o0 += (aA0 * sA + aB0 * sB) * inv;
        o1 += (aA1 * sA + aB1 * sB) * inv;
    }
    float2 r; r.x = o0; r.y = o1;
    *(float2*)&y[(size_t)node * 128 + c0] = r;
}

// ---------------------------------------------------------------------------
// BatchNorm: per-channel stats then apply + ReLU
// ---------------------------------------------------------------------------
__global__ void bn_stats(const float* __restrict__ y, float* __restrict__ gsum,
                         float* __restrict__ gsq) {
    __shared__ float ls[128], lq[128];
    const int tid = threadIdx.x;
    if (tid < 128) { ls[tid] = 0.f; lq[tid] = 0.f; }
    __syncthreads();
    int idx = blockIdx.x * 256 + tid;        // float4 units
    const int stride = gridDim.x * 256;
    const int c4 = (idx & 31) * 4;
    float s[4] = {}, q[4] = {};
    for (; idx < NN * 32; idx += stride) {
        float4 v = ((const float4*)y)[idx];
        s[0] += v.x; q[0] += v.x * v.x;
        s[1] += v.y; q[1] += v.y * v.y;
        s[2] += v.z; q[2] += v.z * v.z;
        s[3] += v.w; q[3] += v.w * v.w;
    }
    #pragma unroll
    for (int j = 0; j < 4; ++j) {
        atomicAdd(&ls[c4 + j], s[j]);
        atomicAdd(&lq[c4 + j], q[j]);
    }
    __syncthreads();
    if (tid < 128) {
        atomicAdd(&gsum[tid], ls[tid]);
        atomicAdd(&gsq[tid],  lq[tid]);
    }
}

__global__ void bn_apply(const float* __restrict__ y, const float* __restrict__ gsum,
                         const float* __restrict__ gsq, const float* __restrict__ gamma,
                         const float* __restrict__ beta, float* __restrict__ out) {
    int idx = blockIdx.x * 256 + threadIdx.x;   // float4 index
    const int stride = gridDim.x * 256;
    const int c4 = (idx & 31) * 4;
    const float invN = 1.f / (float)NN;
    float sc[4], sh[4];
    #pragma unroll
    for (int j = 0; j < 4; ++j) {
        int c = c4 + j;
        float mu  = gsum[c] * invN;
        float var = fmaxf(gsq[c] * invN - mu * mu, 0.f);
        sc[j] = rsqrtf(var + BN_EPS) * gamma[c];
        sh[j] = beta[c] - mu * sc[j];
    }
    for (; idx < NN * 32; idx += stride) {
        float4 v = ((const float4*)y)[idx];
        float4 o;
        o.x = fmaxf(v.x * sc[0] + sh[0], 0.f);
        o.y = fmaxf(v.y * sc[1] + sh[1], 0.f);
        o.z = fmaxf(v.z * sc[2] + sh[2], 0.f);
        o.w = fmaxf(v.w * sc[3] + sh[3], 0.f);
        ((float4*)out)[idx] = o;
    }
}

// ---------------------------------------------------------------------------
extern "C" void kernel_launch(void* const* d_in, const int* in_sizes, int n_in,
                              void* d_out, int out_size, void* d_ws, size_t ws_size,
                              hipStream_t stream) {
    const float* x        = (const float*)d_in[0];
    const int*   eidx     = (const int*)d_in[1];      // [2,E], layout auto-detected
    const float* edge_attr= (const float*)d_in[2];
    const float* Wproj    = (const float*)d_in[3];
    const float* bproj    = (const float*)d_in[4];
    const float* Wl       = (const float*)d_in[5];
    const float* bl       = (const float*)d_in[6];
    const float* Wr       = (const float*)d_in[7];
    const float* br       = (const float*)d_in[8];
    const float* We       = (const float*)d_in[9];
    const float* be       = (const float*)d_in[10];
    const float* att      = (const float*)d_in[11];
    const float* cbias    = (const float*)d_in[12];
    const float* gamma    = (const float*)d_in[13];
    const float* beta     = (const float*)d_in[14];

    char* ws = (char*)d_ws;
    auto alloc = [&](size_t bytes) {
        char* p = ws;
        ws += (bytes + 255) & ~(size_t)255;
        return p;
    };
    float*          h      = (float*)alloc((size_t)NN * 128 * 4);   // pre-BN buffer
    unsigned short* xlB    = (unsigned short*)alloc((size_t)NN * 128 * 2);  // bf16
    float*          xrB    = (float*)alloc((size_t)NN * 128 * 4);
    int*            srcN   = (int*)alloc((size_t)EE * 4);
    int*            dstN   = (int*)alloc((size_t)EE * 4);
    int*            counts = (int*)alloc((size_t)NN * 4);
    int*            offs   = (int*)alloc((size_t)(NN + 1) * 4);
    int*            cursor = (int*)alloc((size_t)NN * 4);
    int*            ssrc   = (int*)alloc((size_t)EE * 4);
    unsigned*       eattrS = (unsigned*)alloc((size_t)EE * 12);     // bf16 x6 sorted
    int*            bsum   = (int*)alloc((size_t)NSB * 4);
    int*            flag   = (int*)alloc(256);
    float*          gsum   = (float*)alloc((size_t)LAYERS * 128 * 4);
    float*          gsq    = (float*)alloc((size_t)LAYERS * 128 * 4);

    hipMemsetAsync(counts, 0, (size_t)NN * 4, stream);
    hipMemsetAsync(gsum, 0, (size_t)LAYERS * 128 * 4, stream);
    hipMemsetAsync(gsq,  0, (size_t)LAYERS * 128 * 4, stream);

    // normalize edge_index to int32 src/dst regardless of int32/int64 layout
    detect_layout<<<1, 1024, 0, stream>>>(eidx, flag);
    normalize_edges<<<(EE + 255) / 256, 256, 0, stream>>>(eidx, flag, srcN, dstN);

    // counting sort by dst; emit src + bf16 edge attrs in sorted order
    count_edges<<<(EE + 255) / 256, 256, 0, stream>>>(dstN, counts);
    scan_partial<<<NSB, 256, 0, stream>>>(counts, bsum);
    scan_bsum<<<1, 64, 0, stream>>>(bsum);
    scan_final<<<NSB, 256, 0, stream>>>(counts, bsum, offs, cursor);
    bucket_edges<<<(EE + 255) / 256, 256, 0, stream>>>(dstN, srcN, edge_attr,
                                                       cursor, ssrc, eattrS);

    // input projection + ReLU
    gemm_k<IN_DIM, true><<<(NN + 31) / 32, 256, 0, stream>>>(x, Wproj, bproj, h, NN);

    for (int l = 0; l < LAYERS; ++l) {
        gemm_dual<<<(NN + 31) / 32, 256, 0, stream>>>(
            h,
            Wl + (size_t)l * 128 * 128, bl + l * 128,
            Wr + (size_t)l * 128 * 128, br + l * 128,
            xlB, xrB, NN);
        gat_agg<<<(NN + 3) / 4, 256, 0, stream>>>(
            xlB, xrB, eattrS, ssrc, offs,
            We + (size_t)l * EDGE_DIM * 128, be + l * 128, att + l * 128,
            cbias + l * 128, h);
        bn_stats<<<400, 256, 0, stream>>>(h, gsum + l * 128, gsq + l * 128);
        float* outp = (l == LAYERS - 1) ? (float*)d_out : h;
        bn_apply<<<512, 256, 0, stream>>>(h, gsum + l * 128, gsq + l * 128,
                                          gamma + l * 128, beta + l * 128, outp);
    }
}

// Round 16
// 590.886 us; speedup vs baseline: 1.6036x; 1.3929x over previous
//
#include <hip/hip_runtime.h>
#include <hip/hip_bf16.h>

#define NN 50000
#define EE 800000
#define IN_DIM 64
#define HIDDEN 128
#define HEADS 4
#define HEAD_DIM 32
#define EDGE_DIM 6
#define LAYERS 2
#define NEG_SLOPE 0.2f
#define BN_EPS 1e-5f

#define SCAN_CHUNK 1024
#define NSB ((NN + SCAN_CHUNK - 1) / SCAN_CHUNK)   // 49 blocks

__device__ __forceinline__ unsigned bf2pack(float a, float b) {
    unsigned ua = __float_as_uint(a); ua = (ua + 0x7FFFu + ((ua >> 16) & 1u)) >> 16;
    unsigned ub = __float_as_uint(b); ub = (ub + 0x7FFFu + ((ub >> 16) & 1u)) >> 16;
    return ua | (ub << 16);
}
__device__ __forceinline__ float bf_lo(unsigned u) { return __uint_as_float(u << 16); }
__device__ __forceinline__ float bf_hi(unsigned u) { return __uint_as_float(u & 0xFFFF0000u); }

// ---------------------------------------------------------------------------
// Edge-index dtype armor: single-block sampled detector (no atomics).
// ---------------------------------------------------------------------------
__global__ void detect_layout(const int* __restrict__ ei, int* __restrict__ flag) {
    __shared__ int any;
    if (threadIdx.x == 0) any = 0;
    __syncthreads();
    int found = 0;
    #pragma unroll
    for (int k = 0; k < 16; ++k) {
        int e = threadIdx.x + k * 1024;       // first 16384 edges; 2e+1 << 1.6M
        if (ei[2 * e + 1] != 0) found = 1;
    }
    if (found) any = 1;                       // benign race: all writers write 1
    __syncthreads();
    if (threadIdx.x == 0) *flag = any;
}

__global__ void normalize_edges(const int* __restrict__ ei, const int* __restrict__ flag,
                                int* __restrict__ src, int* __restrict__ dst) {
    int e = blockIdx.x * 256 + threadIdx.x;
    if (e >= EE) return;
    int s, d;
    if (*flag == 0) {              // int64 layout: low words at even positions
        s = ei[2 * e];
        d = ei[2 * EE + 2 * e];
    } else {                       // int32 layout
        s = ei[e];
        d = ei[EE + e];
    }
    s = (s < 0) ? 0 : ((s >= NN) ? NN - 1 : s);
    d = (d < 0) ? 0 : ((d >= NN) ? NN - 1 : d);
    src[e] = s;
    dst[e] = d;
}

// ---------------------------------------------------------------------------
// Counting sort of edges by destination node
// ---------------------------------------------------------------------------
__global__ void count_edges(const int* __restrict__ dst, int* __restrict__ counts) {
    int e = blockIdx.x * 256 + threadIdx.x;
    if (e < EE) atomicAdd(&counts[dst[e]], 1);
}

__global__ void scan_partial(const int* __restrict__ counts, int* __restrict__ bsum) {
    __shared__ int ws[4];
    const int tid = threadIdx.x;
    const int lane = tid & 63, wid = tid >> 6;
    int i0 = blockIdx.x * SCAN_CHUNK + tid * 4;
    int s = 0;
    #pragma unroll
    for (int k = 0; k < 4; ++k) {
        int i = i0 + k;
        if (i < NN) s += counts[i];
    }
    #pragma unroll
    for (int ofs = 1; ofs < 64; ofs <<= 1) s += __shfl_xor(s, ofs, 64);
    if (lane == 0) ws[wid] = s;
    __syncthreads();
    if (tid == 0) bsum[blockIdx.x] = ws[0] + ws[1] + ws[2] + ws[3];
}

__global__ void scan_bsum(int* __restrict__ bsum) {
    int lane = threadIdx.x;
    int v = (lane < NSB) ? bsum[lane] : 0;
    int x = v;
    #pragma unroll
    for (int ofs = 1; ofs < 64; ofs <<= 1) {
        int t = __shfl_up(x, ofs, 64);
        if (lane >= ofs) x += t;
    }
    if (lane < NSB) bsum[lane] = x - v;   // exclusive
}

__global__ void scan_final(const int* __restrict__ counts, const int* __restrict__ bsumX,
                           int* __restrict__ offsets, int* __restrict__ cursor) {
    __shared__ int ws[4];
    const int tid = threadIdx.x;
    const int lane = tid & 63, wid = tid >> 6;
    const int b = blockIdx.x;
    int i0 = b * SCAN_CHUNK + tid * 4;
    int v[4];
    int tsum = 0;
    #pragma unroll
    for (int k = 0; k < 4; ++k) {
        int i = i0 + k;
        v[k] = (i < NN) ? counts[i] : 0;
        tsum += v[k];
    }
    int x = tsum;
    #pragma unroll
    for (int ofs = 1; ofs < 64; ofs <<= 1) {
        int t = __shfl_up(x, ofs, 64);
        if (lane >= ofs) x += t;
    }
    if (lane == 63) ws[wid] = x;
    __syncthreads();
    int woff = 0;
    for (int w = 0; w < wid; ++w) woff += ws[w];
    int excl = (x - tsum) + woff + bsumX[b];
    #pragma unroll
    for (int k = 0; k < 4; ++k) {
        int i = i0 + k;
        if (i < NN) { offsets[i] = excl; cursor[i] = excl; }
        excl += v[k];
    }
    if (b == 0 && tid == 0) offsets[NN] = EE;
}

// Bucket pass: emit src and edge attrs (bf16) in dst-sorted order, so the hot
// aggregation loop reads only coalesced / line-shared streams.
__global__ void bucket_edges(const int* __restrict__ dst, const int* __restrict__ srcN,
                             const float* __restrict__ ea, int* __restrict__ cursor,
                             int* __restrict__ ssrc, unsigned* __restrict__ eattr_s) {
    int e = blockIdx.x * 256 + threadIdx.x;
    if (e < EE) {
        int p = atomicAdd(&cursor[dst[e]], 1);
        ssrc[p] = srcN[e];
        const float* a = &ea[(size_t)e * EDGE_DIM];
        unsigned* o = eattr_s + (size_t)p * 3;
        o[0] = bf2pack(a[0], a[1]);
        o[1] = bf2pack(a[2], a[3]);
        o[2] = bf2pack(a[4], a[5]);
    }
}

// ---------------------------------------------------------------------------
// fp32 GEMM: out[n,128] = A[n,K] @ W[K,128] + b  (+ReLU). For input proj.
// ---------------------------------------------------------------------------
template <int K, bool RELU>
__launch_bounds__(256, 2)
__global__ void gemm_k(const float* __restrict__ A, const float* __restrict__ W,
                       const float* __restrict__ bias, float* __restrict__ out, int n) {
    constexpr int KC = 64;
    constexpr int NCH = K / KC;
    __shared__ float Ws[KC][128];   // 32 KB
    __shared__ float As[32][KC];    // 8 KB
    const int tid = threadIdx.x;
    const int tx = tid & 31;
    const int ty = tid >> 5;
    const int row0 = blockIdx.x * 32;

    float acc[4][4] = {};

    for (int ch = 0; ch < NCH; ++ch) {
        const float* Wp = W + ch * KC * 128;
        for (int i = tid * 4; i < KC * 128; i += 256 * 4)
            *(float4*)&((float*)Ws)[i] = *(const float4*)&Wp[i];
        for (int i = tid * 4; i < 32 * KC; i += 256 * 4) {
            int r = i / KC, c = i % KC;
            int gr = row0 + r;
            float4 v = {0.f, 0.f, 0.f, 0.f};
            if (gr < n) v = *(const float4*)&A[gr * K + ch * KC + c];
            *(float4*)&As[r][c] = v;
        }
        __syncthreads();

        #pragma unroll 4
        for (int k4 = 0; k4 < KC; k4 += 4) {
            float4 av4[4];
            float aa[4][4];
            #pragma unroll
            for (int i = 0; i < 4; ++i) av4[i] = *(float4*)&As[ty * 4 + i][k4];
            #pragma unroll
            for (int i = 0; i < 4; ++i) {
                aa[i][0] = av4[i].x; aa[i][1] = av4[i].y;
                aa[i][2] = av4[i].z; aa[i][3] = av4[i].w;
            }
            #pragma unroll
            for (int j = 0; j < 4; ++j) {
                float4 w = *(float4*)&Ws[k4 + j][tx * 4];
                #pragma unroll
                for (int i = 0; i < 4; ++i) {
                    acc[i][0] += aa[i][j] * w.x;
                    acc[i][1] += aa[i][j] * w.y;
                    acc[i][2] += aa[i][j] * w.z;
                    acc[i][3] += aa[i][j] * w.w;
                }
            }
        }
        __syncthreads();
    }

    float4 bv = *(const float4*)&bias[tx * 4];
    #pragma unroll
    for (int i = 0; i < 4; ++i) {
        int gr = row0 + ty * 4 + i;
        if (gr < n) {
            float4 o;
            o.x = acc[i][0] + bv.x;
            o.y = acc[i][1] + bv.y;
            o.z = acc[i][2] + bv.z;
            o.w = acc[i][3] + bv.w;
            if (RELU) {
                o.x = fmaxf(o.x, 0.f); o.y = fmaxf(o.y, 0.f);
                o.z = fmaxf(o.z, 0.f); o.w = fmaxf(o.w, 0.f);
            }
            *(float4*)&out[gr * 128 + tx * 4] = o;
        }
    }
}

// ---------------------------------------------------------------------------
// Dual fp32 GEMM sharing the A operand. out1 (xl) stored as bf16 (halves the
// gather traffic downstream); out2 (xr) stays fp32.
// ---------------------------------------------------------------------------
__launch_bounds__(256, 2)
__global__ void gemm_dual(const float* __restrict__ A,
                          const float* __restrict__ W1, const float* __restrict__ b1,
                          const float* __restrict__ W2, const float* __restrict__ b2,
                          unsigned short* __restrict__ out1, float* __restrict__ out2,
                          int n) {
    constexpr int K = 128, KC = 32;
    __shared__ float W1s[KC][128];  // 16 KB
    __shared__ float W2s[KC][128];  // 16 KB
    __shared__ float As[32][KC];    // 4 KB
    const int tid = threadIdx.x;
    const int tx = tid & 31;
    const int ty = tid >> 5;
    const int row0 = blockIdx.x * 32;

    float acc1[4][4] = {}, acc2[4][4] = {};

    for (int ch = 0; ch < K / KC; ++ch) {
        const float* W1p = W1 + ch * KC * 128;
        const float* W2p = W2 + ch * KC * 128;
        for (int i = tid * 4; i < KC * 128; i += 256 * 4) {
            *(float4*)&((float*)W1s)[i] = *(const float4*)&W1p[i];
            *(float4*)&((float*)W2s)[i] = *(const float4*)&W2p[i];
        }
        {
            int i = tid * 4;
            int r = i / KC, c = i % KC;
            int gr = row0 + r;
            float4 v = {0.f, 0.f, 0.f, 0.f};
            if (gr < n) v = *(const float4*)&A[gr * K + ch * KC + c];
            *(float4*)&As[r][c] = v;
        }
        __syncthreads();

        #pragma unroll
        for (int k4 = 0; k4 < KC; k4 += 4) {
            float4 av4[4];
            float aa[4][4];
            #pragma unroll
            for (int i = 0; i < 4; ++i) av4[i] = *(float4*)&As[ty * 4 + i][k4];
            #pragma unroll
            for (int i = 0; i < 4; ++i) {
                aa[i][0] = av4[i].x; aa[i][1] = av4[i].y;
                aa[i][2] = av4[i].z; aa[i][3] = av4[i].w;
            }
            #pragma unroll
            for (int j = 0; j < 4; ++j) {
                float4 w1 = *(float4*)&W1s[k4 + j][tx * 4];
                float4 w2 = *(float4*)&W2s[k4 + j][tx * 4];
                #pragma unroll
                for (int i = 0; i < 4; ++i) {
                    acc1[i][0] += aa[i][j] * w1.x;
                    acc1[i][1] += aa[i][j] * w1.y;
                    acc1[i][2] += aa[i][j] * w1.z;
                    acc1[i][3] += aa[i][j] * w1.w;
                    acc2[i][0] += aa[i][j] * w2.x;
                    acc2[i][1] += aa[i][j] * w2.y;
                    acc2[i][2] += aa[i][j] * w2.z;
                    acc2[i][3] += aa[i][j] * w2.w;
                }
            }
        }
        __syncthreads();
    }

    float4 bv1 = *(const float4*)&b1[tx * 4];
    float4 bv2 = *(const float4*)&b2[tx * 4];
    #pragma unroll
    for (int i = 0; i < 4; ++i) {
        int gr = row0 + ty * 4 + i;
        if (gr < n) {
            float o1x = acc1[i][0] + bv1.x, o1y = acc1[i][1] + bv1.y;
            float o1z = acc1[i][2] + bv1.z, o1w = acc1[i][3] + bv1.w;
            float4 o2;
            o2.x = acc2[i][0] + bv2.x; o2.y = acc2[i][1] + bv2.y;
            o2.z = acc2[i][2] + bv2.z; o2.w = acc2[i][3] + bv2.w;
            uint2 pk;
            pk.x = bf2pack(o1x, o1y);
            pk.y = bf2pack(o1z, o1w);
            *(uint2*)&out1[gr * 128 + tx * 4] = pk;
            *(float4*)&out2[gr * 128 + tx * 4] = o2;
        }
    }
}

// ---------------------------------------------------------------------------
// Fused GATv2 aggregation v4b: identical to v4 but with the R6-proven
// occupancy bound (4 waves/EU -> 128 VGPRs) instead of 8 -> no register
// spill to scratch (R13's 422 MB WRITE_SIZE regression).
// ---------------------------------------------------------------------------
__launch_bounds__(256, 4)
__global__ void gat_agg(const unsigned short* __restrict__ xl,   // bf16 [N][128]
                        const float* __restrict__ xr,
                        const unsigned* __restrict__ eattr_s,    // bf16x6 [E] sorted
                        const int* __restrict__ ssrc,            // [E] sorted src
                        const int* __restrict__ offsets,
                        const float* __restrict__ We, const float* __restrict__ be,
                        const float* __restrict__ att, const float* __restrict__ cbias,
                        float* __restrict__ y) {
    __shared__ float sWe[EDGE_DIM][128];
    __shared__ float sbe[128];
    __shared__ float satt[128];
    __shared__ float scb[128];
    const int tid = threadIdx.x;
    for (int i = tid; i < EDGE_DIM * 128; i += 256) ((float*)sWe)[i] = We[i];
    if (tid < 128) { sbe[tid] = be[tid]; satt[tid] = att[tid]; scb[tid] = cbias[tid]; }
    __syncthreads();

    const int wid = tid >> 6, lane = tid & 63;
    const int node = blockIdx.x * 4 + wid;
    if (node >= NN) return;

    const int c0 = lane * 2;       // this lane's 2 channels
    float2 xrv  = *(const float2*)&xr[(size_t)node * 128 + c0];
    float2 attv = *(const float2*)&satt[c0];
    float2 bev  = *(const float2*)&sbe[c0];
    const float base0 = xrv.x + bev.x;
    const float base1 = xrv.y + bev.y;

    const int off = offsets[node];
    const int deg = offsets[node + 1] - off;

    float mA = -1e30f, dA = 0.f, aA0 = 0.f, aA1 = 0.f;
    float mB = -1e30f, dB = 0.f, aB0 = 0.f, aB1 = 0.f;

    for (int chunk = 0; chunk < deg; chunk += 64) {
        int i = chunk + lane;
        int sL = 0;
        if (i < deg) sL = ssrc[off + i];           // coalesced 4B stream
        const int cnt = min(64, deg - chunk);      // wave-uniform
        const unsigned* ep = eattr_s + (size_t)(off + chunk) * 3;  // uniform base

        for (int j = 0; j < cnt; j += 2) {
            const bool hb = (j + 1 < cnt);          // wave-uniform
            const int jb = hb ? j + 1 : j;          // valid index always
            int sa = __shfl(sL, j, 64);
            int sb = __shfl(sL, jb, 64);
            // two bf16 gathers in flight (4 B per lane, 256 B per wave each)
            unsigned xa_u = *(const unsigned*)&xl[(size_t)sa * 128 + c0];
            unsigned xb_u = *(const unsigned*)&xl[(size_t)sb * 128 + c0];
            // broadcast bf16 edge attrs (uniform address, line-shared)
            unsigned ea0 = ep[j * 3], ea1 = ep[j * 3 + 1], ea2 = ep[j * 3 + 2];
            unsigned eb0 = ep[jb * 3], eb1 = ep[jb * 3 + 1], eb2 = ep[jb * 3 + 2];

            float xa0 = bf_lo(xa_u), xa1 = bf_hi(xa_u);
            float xb0 = bf_lo(xb_u), xb1 = bf_hi(xb_u);
            float eav[6] = {bf_lo(ea0), bf_hi(ea0), bf_lo(ea1),
                            bf_hi(ea1), bf_lo(ea2), bf_hi(ea2)};
            float ebv[6] = {bf_lo(eb0), bf_hi(eb0), bf_lo(eb1),
                            bf_hi(eb1), bf_lo(eb2), bf_hi(eb2)};

            float ma0 = xa0 + base0, ma1 = xa1 + base1;
            float mb0 = xb0 + base0, mb1 = xb1 + base1;
            #pragma unroll
            for (int k = 0; k < EDGE_DIM; ++k) {
                float2 w = *(const float2*)&sWe[k][c0];
                ma0 += eav[k] * w.x; ma1 += eav[k] * w.y;
                mb0 += ebv[k] * w.x; mb1 += ebv[k] * w.y;
            }
            ma0 = (ma0 > 0.f) ? ma0 : ma0 * NEG_SLOPE;
            ma1 = (ma1 > 0.f) ? ma1 : ma1 * NEG_SLOPE;
            mb0 = (mb0 > 0.f) ? mb0 : mb0 * NEG_SLOPE;
            mb1 = (mb1 > 0.f) ? mb1 : mb1 * NEG_SLOPE;
            float ta = ma0 * attv.x + ma1 * attv.y;
            float tb = mb0 * attv.x + mb1 * attv.y;
            // head = 32 channels = 16 consecutive lanes; reduce over bits 0-3
            #pragma unroll
            for (int ofs = 1; ofs <= 8; ofs <<= 1) {
                ta += __shfl_xor(ta, ofs, 64);
                tb += __shfl_xor(tb, ofs, 64);
            }
            {   // state A (edge j always valid)
                float nm = fmaxf(mA, ta);
                float sc = __expf(mA - nm);
                float p  = __expf(ta - nm);
                dA  = dA * sc + p;
                aA0 = aA0 * sc + p * xa0;
                aA1 = aA1 * sc + p * xa1;
                mA = nm;
            }
            if (hb) {   // wave-uniform
                float nm = fmaxf(mB, tb);
                float sc = __expf(mB - nm);
                float p  = __expf(tb - nm);
                dB  = dB * sc + p;
                aB0 = aB0 * sc + p * xb0;
                aB1 = aB1 * sc + p * xb1;
                mB = nm;
            }
        }
    }

    // lane-local merge of states A and B
    float o0 = scb[c0], o1 = scb[c0 + 1];
    if (deg > 0) {
        float M  = fmaxf(mA, mB);
        float sA = __expf(mA - M);      // mB may be -1e30 -> sB underflows to 0
        float sB = __expf(mB - M);
        float den = dA * sA + dB * sB;
        float inv = 1.f / den;
        o0 += (aA0 * sA + aB0 * sB) * inv;
        o1 += (aA1 * sA + aB1 * sB) * inv;
    }
    float2 r; r.x = o0; r.y = o1;
    *(float2*)&y[(size_t)node * 128 + c0] = r;
}

// ---------------------------------------------------------------------------
// BatchNorm: per-channel stats then apply + ReLU
// ---------------------------------------------------------------------------
__global__ void bn_stats(const float* __restrict__ y, float* __restrict__ gsum,
                         float* __restrict__ gsq) {
    __shared__ float ls[128], lq[128];
    const int tid = threadIdx.x;
    if (tid < 128) { ls[tid] = 0.f; lq[tid] = 0.f; }
    __syncthreads();
    int idx = blockIdx.x * 256 + tid;        // float4 units
    const int stride = gridDim.x * 256;
    const int c4 = (idx & 31) * 4;
    float s[4] = {}, q[4] = {};
    for (; idx < NN * 32; idx += stride) {
        float4 v = ((const float4*)y)[idx];
        s[0] += v.x; q[0] += v.x * v.x;
        s[1] += v.y; q[1] += v.y * v.y;
        s[2] += v.z; q[2] += v.z * v.z;
        s[3] += v.w; q[3] += v.w * v.w;
    }
    #pragma unroll
    for (int j = 0; j < 4; ++j) {
        atomicAdd(&ls[c4 + j], s[j]);
        atomicAdd(&lq[c4 + j], q[j]);
    }
    __syncthreads();
    if (tid < 128) {
        atomicAdd(&gsum[tid], ls[tid]);
        atomicAdd(&gsq[tid],  lq[tid]);
    }
}

__global__ void bn_apply(const float* __restrict__ y, const float* __restrict__ gsum,
                         const float* __restrict__ gsq, const float* __restrict__ gamma,
                         const float* __restrict__ beta, float* __restrict__ out) {
    int idx = blockIdx.x * 256 + threadIdx.x;   // float4 index
    const int stride = gridDim.x * 256;
    const int c4 = (idx & 31) * 4;
    const float invN = 1.f / (float)NN;
    float sc[4], sh[4];
    #pragma unroll
    for (int j = 0; j < 4; ++j) {
        int c = c4 + j;
        float mu  = gsum[c] * invN;
        float var = fmaxf(gsq[c] * invN - mu * mu, 0.f);
        sc[j] = rsqrtf(var + BN_EPS) * gamma[c];
        sh[j] = beta[c] - mu * sc[j];
    }
    for (; idx < NN * 32; idx += stride) {
        float4 v = ((const float4*)y)[idx];
        float4 o;
        o.x = fmaxf(v.x * sc[0] + sh[0], 0.f);
        o.y = fmaxf(v.y * sc[1] + sh[1], 0.f);
        o.z = fmaxf(v.z * sc[2] + sh[2], 0.f);
        o.w = fmaxf(v.w * sc[3] + sh[3], 0.f);
        ((float4*)out)[idx] = o;
    }
}

// ---------------------------------------------------------------------------
extern "C" void kernel_launch(void* const* d_in, const int* in_sizes, int n_in,
                              void* d_out, int out_size, void* d_ws, size_t ws_size,
                              hipStream_t stream) {
    const float* x        = (const float*)d_in[0];
    const int*   eidx     = (const int*)d_in[1];      // [2,E], layout auto-detected
    const float* edge_attr= (const float*)d_in[2];
    const float* Wproj    = (const float*)d_in[3];
    const float* bproj    = (const float*)d_in[4];
    const float* Wl       = (const float*)d_in[5];
    const float* bl       = (const float*)d_in[6];
    const float* Wr       = (const float*)d_in[7];
    const float* br       = (const float*)d_in[8];
    const float* We       = (const float*)d_in[9];
    const float* be       = (const float*)d_in[10];
    const float* att      = (const float*)d_in[11];
    const float* cbias    = (const float*)d_in[12];
    const float* gamma    = (const float*)d_in[13];
    const float* beta     = (const float*)d_in[14];

    char* ws = (char*)d_ws;
    auto alloc = [&](size_t bytes) {
        char* p = ws;
        ws += (bytes + 255) & ~(size_t)255;
        return p;
    };
    float*          h      = (float*)alloc((size_t)NN * 128 * 4);   // pre-BN buffer
    unsigned short* xlB    = (unsigned short*)alloc((size_t)NN * 128 * 2);  // bf16
    float*          xrB    = (float*)alloc((size_t)NN * 128 * 4);
    int*            srcN   = (int*)alloc((size_t)EE * 4);
    int*            dstN   = (int*)alloc((size_t)EE * 4);
    int*            counts = (int*)alloc((size_t)NN * 4);
    int*            offs   = (int*)alloc((size_t)(NN + 1) * 4);
    int*            cursor = (int*)alloc((size_t)NN * 4);
    int*            ssrc   = (int*)alloc((size_t)EE * 4);
    unsigned*       eattrS = (unsigned*)alloc((size_t)EE * 12);     // bf16 x6 sorted
    int*            bsum   = (int*)alloc((size_t)NSB * 4);
    int*            flag   = (int*)alloc(256);
    float*          gsum   = (float*)alloc((size_t)LAYERS * 128 * 4);
    float*          gsq    = (float*)alloc((size_t)LAYERS * 128 * 4);

    hipMemsetAsync(counts, 0, (size_t)NN * 4, stream);
    hipMemsetAsync(gsum, 0, (size_t)LAYERS * 128 * 4, stream);
    hipMemsetAsync(gsq,  0, (size_t)LAYERS * 128 * 4, stream);

    // normalize edge_index to int32 src/dst regardless of int32/int64 layout
    detect_layout<<<1, 1024, 0, stream>>>(eidx, flag);
    normalize_edges<<<(EE + 255) / 256, 256, 0, stream>>>(eidx, flag, srcN, dstN);

    // counting sort by dst; emit src + bf16 edge attrs in sorted order
    count_edges<<<(EE + 255) / 256, 256, 0, stream>>>(dstN, counts);
    scan_partial<<<NSB, 256, 0, stream>>>(counts, bsum);
    scan_bsum<<<1, 64, 0, stream>>>(bsum);
    scan_final<<<NSB, 256, 0, stream>>>(counts, bsum, offs, cursor);
    bucket_edges<<<(EE + 255) / 256, 256, 0, stream>>>(dstN, srcN, edge_attr,
                                                       cursor, ssrc, eattrS);

    // input projection + ReLU
    gemm_k<IN_DIM, true><<<(NN + 31) / 32, 256, 0, stream>>>(x, Wproj, bproj, h, NN);

    for (int l = 0; l < LAYERS; ++l) {
        gemm_dual<<<(NN + 31) / 32, 256, 0, stream>>>(
            h,
            Wl + (size_t)l * 128 * 128, bl + l * 128,
            Wr + (size_t)l * 128 * 128, br + l * 128,
            xlB, xrB, NN);
        gat_agg<<<(NN + 3) / 4, 256, 0, stream>>>(
            xlB, xrB, eattrS, ssrc, offs,
            We + (size_t)l * EDGE_DIM * 128, be + l * 128, att + l * 128,
            cbias + l * 128, h);
        bn_stats<<<400, 256, 0, stream>>>(h, gsum + l * 128, gsq + l * 128);
        float* outp = (l == LAYERS - 1) ? (float*)d_out : h;
        bn_apply<<<512, 256, 0, stream>>>(h, gsum + l * 128, gsq + l * 128,
                                          gamma + l * 128, beta + l * 128, outp);
    }
}